// Round 8
// baseline (114.917 us; speedup 1.0000x reference)
//
#include <hip/hip_runtime.h>
#include <hip/hip_bf16.h>

#define LSEQ 4096
#define HDIM 256
#define NS   64
#define PC   32    // number of chunks
#define MC   128   // chunk length (PC*MC == LSEQ)

typedef __attribute__((ext_vector_type(8))) short short8;
typedef __attribute__((ext_vector_type(4))) float floatx4;

__device__ __forceinline__ short b16(float x) {
    __hip_bfloat16 h = __float2bfloat16(x);
    return *(reinterpret_cast<short*>(&h));
}
__device__ __forceinline__ unsigned int pk2(float a, float b) {
    return (unsigned int)(unsigned short)b16(a) | ((unsigned int)(unsigned short)b16(b) << 16);
}
__device__ __forceinline__ void cmul(float& xr, float& xi, float yr, float yi) {
    float r = xr * yr - xi * yi;
    float i = xr * yi + xi * yr;
    xr = r; xi = i;
}

// ---------------- fused LN (stats+normalize+transpose) + W->bf16 conv ----------------
__global__ __launch_bounds__(256) void k_pre(const float* __restrict__ x,
                                             const float* __restrict__ lnw,
                                             const float* __restrict__ lnb,
                                             const float* __restrict__ W1,
                                             const float* __restrict__ W2,
                                             float* __restrict__ xnT,
                                             unsigned short* __restrict__ w1b,
                                             unsigned short* __restrict__ w2b) {
    int t = threadIdx.x;
    if (blockIdx.x >= 256) {   // weight conversion tail blocks
        int g = (blockIdx.x - 256) * 256 + t;
        float4 a = ((const float4*)W1)[g];
        float4 c = ((const float4*)W2)[g];
        ushort4 o1, o2;
        o1.x = (unsigned short)b16(a.x); o1.y = (unsigned short)b16(a.y);
        o1.z = (unsigned short)b16(a.z); o1.w = (unsigned short)b16(a.w);
        o2.x = (unsigned short)b16(c.x); o2.y = (unsigned short)b16(c.y);
        o2.z = (unsigned short)b16(c.z); o2.w = (unsigned short)b16(c.w);
        ((ushort4*)w1b)[g] = o1;
        ((ushort4*)w2b)[g] = o2;
        return;
    }
    __shared__ float tile[16][257];
    __shared__ float smu[16], srs[16];
    int l0 = blockIdx.x * 16;
#pragma unroll
    for (int i = 0; i < 16; ++i)
        tile[i][t] = x[(size_t)(l0 + i) * HDIM + t];
    __syncthreads();
    int wv = t >> 6, lane = t & 63;
#pragma unroll
    for (int k = 0; k < 4; ++k) {
        int i = wv * 4 + k;
        float s = 0.f, s2 = 0.f;
#pragma unroll
        for (int q = 0; q < 4; ++q) {
            float v = tile[i][lane + 64 * q];
            s += v; s2 += v * v;
        }
#pragma unroll
        for (int o = 32; o; o >>= 1) {
            s  += __shfl_xor(s, o);
            s2 += __shfl_xor(s2, o);
        }
        if (lane == 0) {
            float m = s * (1.0f / HDIM);
            smu[i] = m;
            srs[i] = rsqrtf(s2 * (1.0f / HDIM) - m * m + 1e-5f);
        }
    }
    __syncthreads();
    float wh = lnw[t], bh = lnb[t];
    float o[16];
#pragma unroll
    for (int i = 0; i < 16; ++i)
        o[i] = (tile[i][t] - smu[i]) * srs[i] * wh + bh;
    float4* dst = (float4*)(xnT + (size_t)t * LSEQ + l0);
#pragma unroll
    for (int k = 0; k < 4; ++k)
        dst[k] = make_float4(o[4 * k], o[4 * k + 1], o[4 * k + 2], o[4 * k + 3]);
}

// ---------------- shared constant computation ----------------
__device__ __forceinline__ void ssm_consts(const float* Lre, const float* Lim,
                                           const float* Bre, const float* Bim,
                                           float dt, int idx,
                                           float& are, float& aim, float& bre, float& bim) {
    float lre = Lre[idx], lim = Lim[idx];
    float er = expf(lre * dt);
    float sa, ca;
    sincosf(lim * dt, &sa, &ca);
    are = er * ca; aim = er * sa;
    float inv = 1.0f / (lre * lre + lim * lim);
    float nre = are - 1.0f, nim = aim;
    float tre = (nre * lre + nim * lim) * inv;
    float tim = (nim * lre - nre * lim) * inv;
    float br = Bre[idx], bi = Bim[idx];
    bre = tre * br - tim * bi;
    bim = tre * bi + tim * br;
}

// ---------------- MFMA-formulated SSM: one block (16 waves) per h ----------------
// y[t] = sum_{j<=t} K[t-j] u[j]  (Toeplitz GEMM)  + Re(E @ s0)  + D u[t]
// F = M @ U (chunk-final local states), s0 via 32-step fp32 chunk scan.
// 16 waves: each owns one 16x16 MFMA tile per GEMM; M/A' built in parallel.
__global__ __launch_bounds__(1024) void k_scan(const float* __restrict__ xnT,
                                               const float* __restrict__ Lre,
                                               const float* __restrict__ Lim,
                                               const float* __restrict__ Bre,
                                               const float* __restrict__ Bim,
                                               const float* __restrict__ Cre,
                                               const float* __restrict__ Cim,
                                               const float* __restrict__ Dv,
                                               const float* __restrict__ lstep,
                                               __hip_bfloat16* __restrict__ gb,
                                               float* __restrict__ hid,
                                               int interleaved) {
    __shared__ __align__(16) unsigned char ldsb[60672];
    short* ubf = (short*)(ldsb);              // [c][j] bf16, stride 136 (32 rows)
    short* Tm  = (short*)(ldsb + 8704);       // M -> Toeplitz T -> A' ; 128 rows, stride 136
    float* Ff  = (float*)(ldsb + 43520);      // [c]: re at +0..63, im at +65..128; stride 130 f32
    short* S0s = (short*)(ldsb + 43520);      // overlay: [c][2n] bf16, stride 136
    float* Kt  = (float*)(ldsb + 60160);      // K[128] f32

    int h = blockIdx.x;
    int tid = threadIdx.x;
    int wv = __builtin_amdgcn_readfirstlane(tid) >> 6;   // uniform wave id 0..15
    int lane = tid & 63;
    int l15 = lane & 15, q = lane >> 4;
    int mt = wv >> 1, nt = wv & 1;            // this wave's tile (rows 16mt.., chunks 16nt..)
    const float* uh = xnT + (size_t)h * LSEQ;

    float dt = expf(lstep[h]);
    float Dh = Dv[h];

    // per-lane constants for n = lane
    float are, aim, bre, bim;
    ssm_consts(Lre, Lim, Bre, Bim, dt, h * NS + lane, are, aim, bre, bim);
    float cre = Cre[h * NS + lane], cim = Cim[h * NS + lane];

    // power ladder: Ab^2..Ab^64 (per-lane n)
    float A2r = are, A2i = aim;   cmul(A2r, A2i, are, aim);
    float A4r = A2r, A4i = A2i;   cmul(A4r, A4i, A2r, A2i);
    float A8r = A4r, A8i = A4i;   cmul(A8r, A8i, A4r, A4i);
    float A16r = A8r, A16i = A8i;  cmul(A16r, A16i, A8r, A8i);
    float A32r = A16r, A32i = A16i; cmul(A32r, A32i, A16r, A16i);
    float A64r = A32r, A64i = A32i; cmul(A64r, A64i, A32r, A32i);

    // ---- stage u -> ubf (bf16): one float4 per thread ----
    {
        int i4 = tid * 4;
        float4 v = *(const float4*)(uh + i4);
        int c = i4 >> 7, col = i4 & 127;
        unsigned int* d = (unsigned int*)(ubf + c * 136 + col);
        d[0] = pk2(v.x, v.y);
        d[1] = pk2(v.z, v.w);
    }

    // ---- K taps: wave wv computes taps 8wv..8wv+8 ----
    {
        float cbre = cre * bre - cim * bim;
        float cbim = cre * bim + cim * bre;
        float pr = 1.f, pi = 0.f;                 // Ab^(8wv)
        if (wv & 1) cmul(pr, pi, A8r, A8i);
        if (wv & 2) cmul(pr, pi, A16r, A16i);
        if (wv & 4) cmul(pr, pi, A32r, A32i);
        if (wv & 8) cmul(pr, pi, A64r, A64i);
#pragma unroll
        for (int i = 0; i < 8; ++i) {
            float kj = 2.f * (cbre * pr - cbim * pi);
#pragma unroll
            for (int o = 1; o <= 32; o <<= 1) kj += __shfl_xor(kj, o);
            if (lane == 0) Kt[8 * wv + i] = kj;
            cmul(pr, pi, are, aim);
        }
    }

    // ---- M build (parallel): thread (n=lane) fills M[n][j], j in [8wv, 8wv+8) ----
    // M[n][j] = Bb * Ab^(127-j); iterate j downward so exponent climbs by 1.
    {
        int v = 15 - wv;
        float pr = 1.f, pi = 0.f;                 // Ab^(8(15-wv)) = Ab^(120-8wv)
        if (v & 1) cmul(pr, pi, A8r, A8i);
        if (v & 2) cmul(pr, pi, A16r, A16i);
        if (v & 4) cmul(pr, pi, A32r, A32i);
        if (v & 8) cmul(pr, pi, A64r, A64i);
        short8 rr, ri;
#pragma unroll
        for (int i = 0; i < 8; ++i) {             // j = 8wv+7-i, e = 120-8wv+i
            rr[7 - i] = b16(bre * pr - bim * pi);
            ri[7 - i] = b16(bre * pi + bim * pr);
            cmul(pr, pi, are, aim);
        }
        *(short8*)(Tm + lane * 136 + 8 * wv) = rr;          // M_re rows 0..63
        *(short8*)(Tm + (64 + lane) * 136 + 8 * wv) = ri;   // M_im rows 64..127
    }
    __syncthreads();   // ubf, Kt, M ready

    // ---- GEMM1: F = M @ U ; wave wv -> 16x16 tile ----
    {
        floatx4 fa = (floatx4){0.f, 0.f, 0.f, 0.f};
#pragma unroll
        for (int ks = 0; ks < 4; ++ks) {
            short8 am = *(short8*)(Tm + (16 * mt + l15) * 136 + 32 * ks + 8 * q);
            short8 bu = *(short8*)(ubf + (16 * nt + l15) * 136 + 32 * ks + 8 * q);
            fa = __builtin_amdgcn_mfma_f32_16x16x32_bf16(am, bu, fa, 0, 0, 0);
        }
        int c = 16 * nt + l15;
        float* fp = Ff + c * 130;
        int sbase = 16 * mt + 4 * q;              // state index (mt<4: re, mt>=4: im)
#pragma unroll
        for (int reg = 0; reg < 4; ++reg) {
            int s = sbase + reg;
            fp[(mt < 4) ? s : (1 + s)] = fa[reg]; // im block starts at offset 65 = 1+64
        }
    }
    __syncthreads();   // F ready; M consumed

    // ---- concurrent: waves 1..15 build Toeplitz T; wave 0 runs the chunk scan ----
    if (wv != 0) {
#pragma unroll
        for (int it = 0; it < 18; ++it) {
            int idx = it * 960 + (tid - 64);
            if (idx < 128 * 128) {
                int row = idx >> 7, col = idx & 127;
                float kv = Kt[(row - col) & 127];
                Tm[row * 136 + col] = (col <= row) ? b16(kv) : (short)0;
            }
        }
    } else {
        // chunk-level scan: s0 per chunk (bf16 overlay under consumed F rows) + hidden
        float a128r = A64r, a128i = A64i;
        cmul(a128r, a128i, A64r, A64i);
        float sre = 0.f, sim = 0.f;
        for (int c = 0; c < PC; ++c) {
            float fre = Ff[c * 130 + lane];
            float fim = Ff[c * 130 + 65 + lane];
            ((unsigned int*)(ldsb + 43520 + 272 * c))[lane] = pk2(sre, sim);
            float nr = fmaf(a128r, sre, fmaf(-a128i, sim, fre));
            float ni = fmaf(a128r, sim, fmaf( a128i, sre, fim));
            sre = nr; sim = ni;
        }
        if (interleaved) {
            ((float2*)hid)[h * NS + lane] = make_float2(sre, sim);
        } else {
            hid[h * NS + lane] = sre;
        }
    }
    __syncthreads();   // T and S0 ready

    // ---- GEMM2a: Y = T @ U ; wave wv -> 16x16 tile ----
    floatx4 Y = (floatx4){0.f, 0.f, 0.f, 0.f};
#pragma unroll
    for (int ks = 0; ks < 4; ++ks) {
        short8 ta = *(short8*)(Tm + (16 * mt + l15) * 136 + 32 * ks + 8 * q);
        short8 bu = *(short8*)(ubf + (16 * nt + l15) * 136 + 32 * ks + 8 * q);
        Y = __builtin_amdgcn_mfma_f32_16x16x32_bf16(ta, bu, Y, 0, 0, 0);
    }
    __syncthreads();   // T consumed

    // ---- A' build: wave wv -> rows 8wv..8wv+8 ; A'[t][2n,2n+1] = 2Re/-2Im(C*Ab^(t+1)) ----
    {
        float pr = are, pi = aim;                 // Ab^(8wv+1)
        if (wv & 1) cmul(pr, pi, A8r, A8i);
        if (wv & 2) cmul(pr, pi, A16r, A16i);
        if (wv & 4) cmul(pr, pi, A32r, A32i);
        if (wv & 8) cmul(pr, pi, A64r, A64i);
#pragma unroll
        for (int i = 0; i < 8; ++i) {
            int t = 8 * wv + i;
            float er =  2.f * (cre * pr - cim * pi);
            float en = -2.f * (cre * pi + cim * pr);
            ((unsigned int*)(ldsb + 8704 + 272 * t))[lane] = pk2(er, en);
            cmul(pr, pi, are, aim);
        }
    }
    __syncthreads();   // A' ready

    // ---- GEMM2b: Y += A' @ S0' (k = 128 packed 2n) ----
#pragma unroll
    for (int ks = 0; ks < 4; ++ks) {
        short8 ea = *(short8*)(Tm + (16 * mt + l15) * 136 + 32 * ks + 8 * q);
        short8 sf = *(short8*)(S0s + (16 * nt + l15) * 136 + 32 * ks + 8 * q);
        Y = __builtin_amdgcn_mfma_f32_16x16x32_bf16(ea, sf, Y, 0, 0, 0);
    }

    // ---- epilogue: + D*u, GELU, scatter gb[l][h] ----
    {
        int c = 16 * nt + l15;
#pragma unroll
        for (int reg = 0; reg < 4; ++reg) {
            int t = 16 * mt + 4 * q + reg;        // C/D: row=(lane>>4)*4+reg, col=lane&15
            int l = c * MC + t;
            float u = uh[l];
            float y = Y[reg] + Dh * u;
            float z = 0.7978845608028654f * fmaf(0.044715f, y * y * y, y);
            float e = __expf(2.f * z);
            float th = 1.f - 2.f / (e + 1.f);
            float gg = 0.5f * y * (1.f + th);
            gb[((size_t)l << 8) + h] = __float2bfloat16(gg);
        }
    }
}

// ---------------- GLU epilogue via MFMA: 2048 one-wave blocks, 32x16 tiles ----------------
__global__ __launch_bounds__(64) void k_glu_mfma(const unsigned short* __restrict__ gbs,
                                                 const unsigned short* __restrict__ w1b,
                                                 const unsigned short* __restrict__ w2b,
                                                 const float* __restrict__ b1v,
                                                 const float* __restrict__ b2v,
                                                 const float* __restrict__ x,
                                                 float* __restrict__ out) {
    int bx = blockIdx.x;
    int m0 = (bx >> 4) * 32;        // 128 m-tiles
    int n0 = (bx & 15) * 16;        // 16 n-tiles
    int lane = threadIdx.x;
    int t = lane & 15, q = lane >> 4;

    floatx4 acc[2][2];              // [mt][{W1,W2}]
    acc[0][0] = (floatx4){0,0,0,0}; acc[0][1] = (floatx4){0,0,0,0};
    acc[1][0] = (floatx4){0,0,0,0}; acc[1][1] = (floatx4){0,0,0,0};

    const unsigned short* A0 = gbs + (size_t)(m0 + t) * HDIM + q * 8;
    const unsigned short* A1 = A0 + 16 * HDIM;
    const unsigned short* B1 = w1b + (size_t)(n0 + t) * HDIM + q * 8;
    const unsigned short* B2 = w2b + (size_t)(n0 + t) * HDIM + q * 8;

#pragma unroll
    for (int ks = 0; ks < 8; ++ks) {
        int off = ks * 32;
        short8 a0 = *(const short8*)(A0 + off);
        short8 a1 = *(const short8*)(A1 + off);
        short8 b1 = *(const short8*)(B1 + off);
        short8 b2 = *(const short8*)(B2 + off);
        acc[0][0] = __builtin_amdgcn_mfma_f32_16x16x32_bf16(a0, b1, acc[0][0], 0, 0, 0);
        acc[1][0] = __builtin_amdgcn_mfma_f32_16x16x32_bf16(a1, b1, acc[1][0], 0, 0, 0);
        acc[0][1] = __builtin_amdgcn_mfma_f32_16x16x32_bf16(a0, b2, acc[0][1], 0, 0, 0);
        acc[1][1] = __builtin_amdgcn_mfma_f32_16x16x32_bf16(a1, b2, acc[1][1], 0, 0, 0);
    }

    int hh = n0 + t;
    float bb1 = b1v[hh], bb2 = b2v[hh];
#pragma unroll
    for (int mt = 0; mt < 2; ++mt) {
#pragma unroll
        for (int reg = 0; reg < 4; ++reg) {
            int l = m0 + mt * 16 + q * 4 + reg;   // C/D: row=(lane>>4)*4+reg, col=lane&15
            float a  = acc[mt][0][reg] + bb1;
            float sg = 1.f / (1.f + __expf(-(acc[mt][1][reg] + bb2)));
            out[(size_t)l * HDIM + hh] = fmaf(a, sg, x[(size_t)l * HDIM + hh]);
        }
    }
}

extern "C" void kernel_launch(void* const* d_in, const int* in_sizes, int n_in,
                              void* d_out, int out_size, void* d_ws, size_t ws_size,
                              hipStream_t stream) {
    (void)in_sizes; (void)n_in; (void)ws_size;
    const float* x     = (const float*)d_in[0];
    const float* Lre   = (const float*)d_in[1];
    const float* Lim   = (const float*)d_in[2];
    const float* Bre   = (const float*)d_in[3];
    const float* Bim   = (const float*)d_in[4];
    const float* Cre   = (const float*)d_in[5];
    const float* Cim   = (const float*)d_in[6];
    const float* Dv    = (const float*)d_in[7];
    const float* lstep = (const float*)d_in[8];
    const float* lnw   = (const float*)d_in[9];
    const float* lnb   = (const float*)d_in[10];
    const float* W1    = (const float*)d_in[11];
    const float* b1    = (const float*)d_in[12];
    const float* W2    = (const float*)d_in[13];
    const float* b2    = (const float*)d_in[14];

    float* ws   = (float*)d_ws;
    float* xnT  = ws;                                     // H*L fp32
    unsigned short* gb  = (unsigned short*)(xnT + (size_t)HDIM * LSEQ);  // L*H bf16
    unsigned short* w1b = gb + (size_t)LSEQ * HDIM;       // H*H bf16
    unsigned short* w2b = w1b + HDIM * HDIM;              // H*H bf16

    int interleaved = (out_size == LSEQ * HDIM + 2 * HDIM * NS) ? 1 : 0;
    float* hid  = (float*)d_out;
    float* outp = (float*)d_out + (interleaved ? 2 * HDIM * NS : HDIM * NS);

    k_pre      <<<256 + 64, 256, 0, stream>>>(x, lnw, lnb, W1, W2, xnT, w1b, w2b);
    k_scan     <<<HDIM, 1024, 0, stream>>>(xnT, Lre, Lim, Bre, Bim, Cre, Cim,
                                           Dv, lstep, (__hip_bfloat16*)gb, hid, interleaved);
    k_glu_mfma <<<128 * 16, 64, 0, stream>>>(gb, w1b, w2b, b1, b2, x, outp);
}